// Round 3
// baseline (728.563 us; speedup 1.0000x reference)
//
#include <hip/hip_runtime.h>
#include <hip/hip_bf16.h>
#include <stdint.h>
#include <stddef.h>

typedef __attribute__((ext_vector_type(8))) short short8;
typedef __attribute__((ext_vector_type(4))) float f32x4;

#define NTOK 32768
#define DIN 512
#define HID 1024
#define DOUT 256
#define NEXP 10
#define TM 128

__device__ __forceinline__ unsigned short f2bf(float f) {
  unsigned int u = __float_as_uint(f);
  u += 0x7fffu + ((u >> 16) & 1u);   // round-to-nearest-even
  return (unsigned short)(u >> 16);
}

// async 16B/lane global->LDS DMA (dest = wave-uniform base + lane*16)
__device__ __forceinline__ void gld16(void* lds, const void* g) {
  __builtin_amdgcn_global_load_lds(
      (const __attribute__((address_space(1))) unsigned int*)g,
      (__attribute__((address_space(3))) unsigned int*)lds, 16, 0, 0);
}

// ---------------- Wr transpose: [512][10] f32 -> [10][512] f32 -------------
__global__ void k_transpose_wr(const float* __restrict__ wr, float* __restrict__ wrt) {
  for (int i = threadIdx.x; i < DIN * NEXP; i += 256) {
    int d = i / NEXP, e = i % NEXP;
    wrt[e * DIN + d] = wr[i];
  }
}

// ---------- generic [E][R][C] f32 -> [E][C][R] bf16 (ushort bits) ----------
__global__ __launch_bounds__(256) void k_transpose_conv(
    const float* __restrict__ in, unsigned short* __restrict__ out, int R, int C) {
  __shared__ unsigned short tile[64][72];
  int tid = threadIdx.x;
  const float* ip = in + ((size_t)blockIdx.z * R + blockIdx.y * 64) * C + blockIdx.x * 64;
  int r = tid >> 2, c0 = (tid & 3) * 16;
  const float* p = ip + (size_t)r * C + c0;
#pragma unroll
  for (int j = 0; j < 16; j += 4) {
    float4 v = *(const float4*)(p + j);
    tile[r][c0 + j + 0] = f2bf(v.x);
    tile[r][c0 + j + 1] = f2bf(v.y);
    tile[r][c0 + j + 2] = f2bf(v.z);
    tile[r][c0 + j + 3] = f2bf(v.w);
  }
  __syncthreads();
  unsigned short* op = out + ((size_t)blockIdx.z * C + blockIdx.x * 64) * R + blockIdx.y * 64;
  int c = tid >> 2, r0 = (tid & 3) * 16;
  unsigned short* q = op + (size_t)c * R + r0;
  union { short8 v; unsigned short u[8]; } t0, t1;
#pragma unroll
  for (int j = 0; j < 8; j++) { t0.u[j] = tile[r0 + j][c]; t1.u[j] = tile[r0 + 8 + j][c]; }
  *(short8*)(q) = t0.v;
  *(short8*)(q + 8) = t1.v;
}

// ------------- router phase 1: top-2 + per-block hist + x->bf16 ------------
__global__ __launch_bounds__(256) void k_router(
    const float* __restrict__ x, const float* __restrict__ spike,
    const float* __restrict__ wrt, const float* __restrict__ br,
    unsigned short* __restrict__ xb, int* __restrict__ topi,
    float2* __restrict__ topw, int* __restrict__ histG) {
  __shared__ int hist[16];
  int tid = threadIdx.x, wave = tid >> 6, lane = tid & 63;
  if (tid < 16) hist[tid] = 0;
  __syncthreads();
  for (int t = 0; t < 16; t++) {
    int b = blockIdx.x * 64 + wave * 16 + t;
    const float* xr = x + (size_t)b * DIN;
    float xv[8];
#pragma unroll
    for (int k = 0; k < 8; k++) xv[k] = xr[lane + 64 * k];   // coalesced
    unsigned short* xo = xb + (size_t)b * DIN;
#pragma unroll
    for (int k = 0; k < 8; k++) xo[lane + 64 * k] = f2bf(xv[k]);
    float lg[NEXP];
#pragma unroll
    for (int e = 0; e < NEXP; e++) {
      const float* w = wrt + e * DIN;
      float s = 0.f;
#pragma unroll
      for (int k = 0; k < 8; k++) s += xv[k] * w[lane + 64 * k];
      lg[e] = s;
    }
#pragma unroll
    for (int off = 32; off > 0; off >>= 1) {
#pragma unroll
      for (int e = 0; e < NEXP; e++) lg[e] += __shfl_xor(lg[e], off);
    }
    float sv = spike[(size_t)b * 16 + (lane & 15)];
    sv += __shfl_xor(sv, 8); sv += __shfl_xor(sv, 4);
    sv += __shfl_xor(sv, 2); sv += __shfl_xor(sv, 1);
    float avg = sv * 0.0625f;
#pragma unroll
    for (int e = 0; e < NEXP; e++) lg[e] += br[e];
    lg[8] += avg; lg[9] += avg;
    float mx = lg[0];
#pragma unroll
    for (int e = 1; e < NEXP; e++) mx = fmaxf(mx, lg[e]);
    float p[NEXP], ps = 0.f;
#pragma unroll
    for (int e = 0; e < NEXP; e++) { p[e] = __expf(lg[e] - mx); ps += p[e]; }
    int i0 = 0; float p0 = p[0];
#pragma unroll
    for (int e = 1; e < NEXP; e++) if (p[e] > p0) { p0 = p[e]; i0 = e; }
    float p1 = -1.f; int i1 = 0;
#pragma unroll
    for (int e = 0; e < NEXP; e++) if (e != i0 && p[e] > p1) { p1 = p[e]; i1 = e; }
    float inv = 1.f / (p0 + p1 + ps * 1e-9f);
    if (lane == 0) {
      topi[b] = i0 | (i1 << 8);
      topw[b] = make_float2(p0 * inv, p1 * inv);
      atomicAdd(&hist[i0], 1); atomicAdd(&hist[i1], 1);   // LDS only
    }
  }
  __syncthreads();
  if (tid < 16) histG[blockIdx.x * 16 + tid] = hist[tid];
}

// ------------- router phase 2: per-expert prefix over 512 blocks -----------
__global__ void k_scan(const int* __restrict__ histG, int* __restrict__ blockBase,
                       int* __restrict__ cnt) {
  int w = threadIdx.x >> 6;     // expert id (one wave each)
  int lane = threadIdx.x & 63;
  if (w >= NEXP) return;
  int carry = 0;
  for (int c = 0; c < 8; c++) {
    int idx = (c * 64 + lane) * 16 + w;
    int v = histG[idx];
    int incl = v;
#pragma unroll
    for (int d = 1; d < 64; d <<= 1) { int u = __shfl_up(incl, d); if (lane >= d) incl += u; }
    blockBase[idx] = carry + incl - v;
    carry += __shfl(incl, 63);
  }
  if (lane == 0) cnt[w] = carry;
}

// ------------- router phase 3: scatter token ids into expert lists ---------
__global__ void k_scatter(const int* __restrict__ topi, const float2* __restrict__ topw,
                          const int* __restrict__ blockBase,
                          unsigned short* __restrict__ tok, float* __restrict__ wgt) {
  __shared__ int loc[16];
  int tid = threadIdx.x;
  if (tid < 16) loc[tid] = 0;
  __syncthreads();
  int t = blockIdx.x * 64 + tid;
  int pk = topi[t];
  float2 w = topw[t];
  int i0 = pk & 255, i1 = (pk >> 8) & 255;
  int s0 = blockBase[blockIdx.x * 16 + i0] + atomicAdd(&loc[i0], 1);
  tok[i0 * NTOK + s0] = (unsigned short)t; wgt[i0 * NTOK + s0] = w.x;
  int s1 = blockBase[blockIdx.x * 16 + i1] + atomicAdd(&loc[i1], 1);
  tok[i1 * NTOK + s1] = (unsigned short)t; wgt[i1 * NTOK + s1] = w.y;
}

// --------- fused grouped expert kernel: out += w * (relu(x W1 + b1) W2 + b2)
// Tile M=128 tokens x N=256 out, hidden chunk HC=128 (8 chunks), BK=64.
// 4 waves 2x2 (each 64 rows x 128 cols). LDS: wbuf 32K (GEMM1 xa|b1s aliased
// with GEMM2 b2s) + hs 32K = 66 KB -> 2 blocks/CU.
__global__ __launch_bounds__(256, 2) void k_moe(
    const unsigned short* __restrict__ xb, const unsigned short* __restrict__ w1t,
    const unsigned short* __restrict__ w2t, const float* __restrict__ b1,
    const float* __restrict__ b2, const int* __restrict__ cnt,
    const unsigned short* __restrict__ tok, const float* __restrict__ wgt,
    float* __restrict__ out) {
  int e = blockIdx.y;
  int n = cnt[e];
  int tile = blockIdx.x;
  if (tile * TM >= n) return;
  __shared__ unsigned short wbuf[16384];   // 32 KB phase-aliased
  __shared__ unsigned short hs[16384];     // 32 KB h chunk [128 tok x 128 h]
  __shared__ int stok[TM];
  __shared__ float swgt[TM];
  int tid = threadIdx.x;
  if (tid < TM) {
    int idx = tile * TM + tid;
    bool v = idx < n;
    stok[tid] = v ? (int)tok[e * NTOK + idx] : 0;
    swgt[tid] = v ? wgt[e * NTOK + idx] : 0.f;
  }
  __syncthreads();
  int wave = tid >> 6, lane = tid & 63, quad = lane >> 4, l16 = lane & 15;
  int wm = wave & 1, wn = wave >> 1;
  // staging: thread owns 16B chunk at (row = j*32 + srow, lds slot = tid&7)
  int srow = tid >> 3;
  int c8 = (tid & 7) ^ (srow & 7);         // inverse swizzle on source column
  const unsigned short* gx[4];
#pragma unroll
  for (int j = 0; j < 4; j++)
    gx[j] = xb + (size_t)stok[j * 32 + srow] * DIN + c8 * 8;
  const unsigned short* w1e = w1t + (size_t)e * HID * DIN;   // [h][d]
  const unsigned short* w2e = w2t + (size_t)e * DOUT * HID;  // [o][h]
  const unsigned short* gb1 = w1e + (size_t)srow * DIN + c8 * 8;
  const unsigned short* gb2 = w2e + (size_t)srow * HID + c8 * 8;
  f32x4 acc2[4][8];
#pragma unroll
  for (int nt = 0; nt < 8; nt++) {
    float bv = b2[e * DOUT + wn * 128 + nt * 16 + l16];
#pragma unroll
    for (int mt = 0; mt < 4; mt++) acc2[mt][nt] = (f32x4){bv, bv, bv, bv};
  }
  for (int hc = 0; hc < 8; hc++) {
    // ========== GEMM1: h[128x128] = x[128x512] @ W1T-chunk, +b1, relu ======
    f32x4 acc1[4][4];
#pragma unroll
    for (int nt = 0; nt < 4; nt++) {
      float bv = b1[e * HID + hc * 128 + wn * 64 + nt * 16 + l16];
#pragma unroll
      for (int mt = 0; mt < 4; mt++) acc1[mt][nt] = (f32x4){bv, bv, bv, bv};
    }
    for (int ks = 0; ks < 8; ks++) {
      __syncthreads();                     // wbuf readers (prev slab / b2s) done
#pragma unroll
      for (int j = 0; j < 4; j++)
        gld16(wbuf + ((size_t)j * 256 + tid) * 8, gx[j] + ks * 64);
#pragma unroll
      for (int j = 0; j < 4; j++)
        gld16(wbuf + 8192 + ((size_t)j * 256 + tid) * 8,
              gb1 + ((size_t)hc * 128 + j * 32) * DIN + ks * 64);
      __syncthreads();                     // DMA drained
#pragma unroll
      for (int ki2 = 0; ki2 < 2; ki2++) {
        int cq = ki2 * 4 + quad;
        short8 af[4], bf[4];
#pragma unroll
        for (int mt = 0; mt < 4; mt++) {
          int r = wm * 64 + mt * 16 + l16;
          af[mt] = *(const short8*)(wbuf + (r * 8 + (cq ^ (r & 7))) * 8);
        }
#pragma unroll
        for (int nt = 0; nt < 4; nt++) {
          int r = wn * 64 + nt * 16 + l16;
          bf[nt] = *(const short8*)(wbuf + 8192 + (r * 8 + (cq ^ (r & 7))) * 8);
        }
#pragma unroll
        for (int mt = 0; mt < 4; mt++)
#pragma unroll
          for (int nt = 0; nt < 4; nt++)
            acc1[mt][nt] = __builtin_amdgcn_mfma_f32_16x16x32_bf16(
                af[mt], bf[nt], acc1[mt][nt], 0, 0, 0);
      }
    }
    // relu + bf16 -> swizzled hs
#pragma unroll
    for (int mt = 0; mt < 4; mt++) {
#pragma unroll
      for (int nt = 0; nt < 4; nt++) {
        int col = wn * 64 + nt * 16 + l16;
        int c16 = col >> 3, co = col & 7;
#pragma unroll
        for (int r4 = 0; r4 < 4; r4++) {
          int r = wm * 64 + mt * 16 + quad * 4 + r4;
          float v = acc1[mt][nt][r4];
          hs[(r * 16 + (c16 ^ (r & 15))) * 8 + co] = f2bf(v > 0.f ? v : 0.f);
        }
      }
    }
    // ========== GEMM2: acc2 += h[128x128] @ W2T-chunk =======================
    for (int k2 = 0; k2 < 2; k2++) {
      __syncthreads();                     // hs written; prev wbuf reads done
#pragma unroll
      for (int j = 0; j < 8; j++)
        gld16(wbuf + ((size_t)j * 256 + tid) * 8,
              gb2 + (size_t)j * 32 * HID + hc * 128 + k2 * 64);
      __syncthreads();
#pragma unroll
      for (int ki2 = 0; ki2 < 2; ki2++) {
        int cq = ki2 * 4 + quad;
        int ch = k2 * 8 + cq;
        short8 af[4];
#pragma unroll
        for (int mt = 0; mt < 4; mt++) {
          int r = wm * 64 + mt * 16 + l16;
          af[mt] = *(const short8*)(hs + (r * 16 + (ch ^ (r & 15))) * 8);
        }
#pragma unroll
        for (int g = 0; g < 2; g++) {      // nt-grouped: caps live B-frags at 4
          short8 bf[4];
#pragma unroll
          for (int nt = 0; nt < 4; nt++) {
            int r = wn * 128 + g * 64 + nt * 16 + l16;
            bf[nt] = *(const short8*)(wbuf + (r * 8 + (cq ^ (r & 7))) * 8);
          }
#pragma unroll
          for (int mt = 0; mt < 4; mt++)
#pragma unroll
            for (int nt = 0; nt < 4; nt++)
              acc2[mt][g * 4 + nt] = __builtin_amdgcn_mfma_f32_16x16x32_bf16(
                  af[mt], bf[nt], acc2[mt][g * 4 + nt], 0, 0, 0);
        }
      }
    }
  }
  // ---- epilogue: gate-weighted atomic accumulate ----
#pragma unroll
  for (int mt = 0; mt < 4; mt++) {
#pragma unroll
    for (int r4 = 0; r4 < 4; r4++) {
      int m = wm * 64 + mt * 16 + quad * 4 + r4;
      float wv = swgt[m];
      if (wv != 0.f) {
        int t = stok[m];
        float* op = out + (size_t)t * DOUT + wn * 128 + l16;
#pragma unroll
        for (int nt = 0; nt < 8; nt++)
          atomicAdd(op + nt * 16, acc2[mt][nt][r4] * wv);
      }
    }
  }
}

extern "C" void kernel_launch(void* const* d_in, const int* in_sizes, int n_in,
                              void* d_out, int out_size, void* d_ws, size_t ws_size,
                              hipStream_t stream) {
  (void)in_sizes; (void)n_in; (void)ws_size;
  const float* x     = (const float*)d_in[0];
  const float* spike = (const float*)d_in[1];
  const float* Wr    = (const float*)d_in[2];
  const float* br    = (const float*)d_in[3];
  const float* W1    = (const float*)d_in[4];
  const float* b1    = (const float*)d_in[5];
  const float* W2    = (const float*)d_in[6];
  const float* b2    = (const float*)d_in[7];
  float* out = (float*)d_out;
  char* ws = (char*)d_ws;
  unsigned short* xb   = (unsigned short*)(ws + 0);          // 33,554,432
  unsigned short* w1t  = (unsigned short*)(ws + 33554432);   // 10,485,760
  unsigned short* w2t  = (unsigned short*)(ws + 44040192);   //  5,242,880
  float* wrt           = (float*)(ws + 49283072);            //     20,480
  int*   cnt           = (int*)(ws + 49303552);              //         64
  unsigned short* tok  = (unsigned short*)(ws + 49303616);   //    655,360
  float* wgt           = (float*)(ws + 49958976);            //  1,310,720
  int*   topi          = (int*)(ws + 51269696);              //    131,072
  float2* topw         = (float2*)(ws + 51400768);           //    262,144
  int*   histG         = (int*)(ws + 51662912);              //     32,768
  int*   blockBase     = (int*)(ws + 51695680);              //     32,768

  hipMemsetAsync(out, 0, (size_t)out_size * sizeof(float), stream);
  k_transpose_wr<<<1, 256, 0, stream>>>(Wr, wrt);
  k_transpose_conv<<<dim3(16, 8, 10), 256, 0, stream>>>(W1, w1t, DIN, HID);
  k_transpose_conv<<<dim3(4, 16, 10), 256, 0, stream>>>(W2, w2t, HID, DOUT);
  k_router<<<512, 256, 0, stream>>>(x, spike, wrt, br, xb, topi, topw, histG);
  k_scan<<<1, 640, 0, stream>>>(histG, blockBase, cnt);
  k_scatter<<<512, 64, 0, stream>>>(topi, topw, blockBase, tok, wgt);
  k_moe<<<dim3(256, NEXP), 256, 0, stream>>>(xb, w1t, w2t, b1, b2, cnt, tok, wgt, out);
}

// Round 4
// 694.493 us; speedup vs baseline: 1.0491x; 1.0491x over previous
//
#include <hip/hip_runtime.h>
#include <hip/hip_bf16.h>
#include <stdint.h>
#include <stddef.h>

typedef __attribute__((ext_vector_type(8))) short short8;
typedef __attribute__((ext_vector_type(4))) float f32x4;

#define NTOK 32768
#define DIN 512
#define HID 1024
#define DOUT 256
#define NEXP 10
#define TM 128
#define MAXTILE 528   // 8 XCD groups x 66

__device__ __forceinline__ unsigned short f2bf(float f) {
  unsigned int u = __float_as_uint(f);
  u += 0x7fffu + ((u >> 16) & 1u);   // round-to-nearest-even
  return (unsigned short)(u >> 16);
}

// async 16B/lane global->LDS DMA (dest = wave-uniform base + lane*16)
__device__ __forceinline__ void gld16(void* lds, const void* g) {
  __builtin_amdgcn_global_load_lds(
      (const __attribute__((address_space(1))) unsigned int*)g,
      (__attribute__((address_space(3))) unsigned int*)lds, 16, 0, 0);
}

// ---------------- Wr transpose: [512][10] f32 -> [10][512] f32 -------------
__global__ void k_transpose_wr(const float* __restrict__ wr, float* __restrict__ wrt) {
  for (int i = threadIdx.x; i < DIN * NEXP; i += 256) {
    int d = i / NEXP, e = i % NEXP;
    wrt[e * DIN + d] = wr[i];
  }
}

// ---------- generic [E][R][C] f32 -> [E][C][R] bf16 (ushort bits) ----------
__global__ __launch_bounds__(256) void k_transpose_conv(
    const float* __restrict__ in, unsigned short* __restrict__ out, int R, int C) {
  __shared__ unsigned short tile[64][72];
  int tid = threadIdx.x;
  const float* ip = in + ((size_t)blockIdx.z * R + blockIdx.y * 64) * C + blockIdx.x * 64;
  int r = tid >> 2, c0 = (tid & 3) * 16;
  const float* p = ip + (size_t)r * C + c0;
#pragma unroll
  for (int j = 0; j < 16; j += 4) {
    float4 v = *(const float4*)(p + j);
    tile[r][c0 + j + 0] = f2bf(v.x);
    tile[r][c0 + j + 1] = f2bf(v.y);
    tile[r][c0 + j + 2] = f2bf(v.z);
    tile[r][c0 + j + 3] = f2bf(v.w);
  }
  __syncthreads();
  unsigned short* op = out + ((size_t)blockIdx.z * C + blockIdx.x * 64) * R + blockIdx.y * 64;
  int c = tid >> 2, r0 = (tid & 3) * 16;
  unsigned short* q = op + (size_t)c * R + r0;
  union { short8 v; unsigned short u[8]; } t0, t1;
#pragma unroll
  for (int j = 0; j < 8; j++) { t0.u[j] = tile[r0 + j][c]; t1.u[j] = tile[r0 + 8 + j][c]; }
  *(short8*)(q) = t0.v;
  *(short8*)(q + 8) = t1.v;
}

// ------------- router phase 1: top-2 + per-block hist ----------------------
__global__ __launch_bounds__(256) void k_router(
    const float* __restrict__ x, const float* __restrict__ spike,
    const float* __restrict__ wrt, const float* __restrict__ br,
    int* __restrict__ topi, float2* __restrict__ topw, int* __restrict__ histG) {
  __shared__ int hist[16];
  int tid = threadIdx.x, wave = tid >> 6, lane = tid & 63;
  if (tid < 16) hist[tid] = 0;
  __syncthreads();
  for (int t = 0; t < 16; t++) {
    int b = blockIdx.x * 64 + wave * 16 + t;
    const float* xr = x + (size_t)b * DIN;
    float xv[8];
#pragma unroll
    for (int k = 0; k < 8; k++) xv[k] = xr[lane + 64 * k];   // coalesced
    float lg[NEXP];
#pragma unroll
    for (int e = 0; e < NEXP; e++) {
      const float* w = wrt + e * DIN;
      float s = 0.f;
#pragma unroll
      for (int k = 0; k < 8; k++) s += xv[k] * w[lane + 64 * k];
      lg[e] = s;
    }
#pragma unroll
    for (int off = 32; off > 0; off >>= 1) {
#pragma unroll
      for (int e = 0; e < NEXP; e++) lg[e] += __shfl_xor(lg[e], off);
    }
    float sv = spike[(size_t)b * 16 + (lane & 15)];
    sv += __shfl_xor(sv, 8); sv += __shfl_xor(sv, 4);
    sv += __shfl_xor(sv, 2); sv += __shfl_xor(sv, 1);
    float avg = sv * 0.0625f;
#pragma unroll
    for (int e = 0; e < NEXP; e++) lg[e] += br[e];
    lg[8] += avg; lg[9] += avg;
    float mx = lg[0];
#pragma unroll
    for (int e = 1; e < NEXP; e++) mx = fmaxf(mx, lg[e]);
    float p[NEXP], ps = 0.f;
#pragma unroll
    for (int e = 0; e < NEXP; e++) { p[e] = __expf(lg[e] - mx); ps += p[e]; }
    int i0 = 0; float p0 = p[0];
#pragma unroll
    for (int e = 1; e < NEXP; e++) if (p[e] > p0) { p0 = p[e]; i0 = e; }
    float p1 = -1.f; int i1 = 0;
#pragma unroll
    for (int e = 0; e < NEXP; e++) if (e != i0 && p[e] > p1) { p1 = p[e]; i1 = e; }
    float inv = 1.f / (p0 + p1 + ps * 1e-9f);
    if (lane == 0) {
      topi[b] = i0 | (i1 << 8);
      topw[b] = make_float2(p0 * inv, p1 * inv);
      atomicAdd(&hist[i0], 1); atomicAdd(&hist[i1], 1);   // LDS only
    }
  }
  __syncthreads();
  if (tid < 16) histG[blockIdx.x * 16 + tid] = hist[tid];
}

// -------- router phase 2: global pair bases + dense XCD-groupable tiles ----
__global__ void k_scan(const int* __restrict__ histG, int* __restrict__ baseG,
                       int* __restrict__ cnt, int* __restrict__ tileE,
                       int* __restrict__ tileS, int* __restrict__ tileN) {
  __shared__ int scnt[16];
  int tid = threadIdx.x;
  int w = tid >> 6, lane = tid & 63;           // 10 waves, one per expert
  for (int i = tid; i < MAXTILE; i += 640) tileE[i] = -1;
  // pass 1: per-expert totals
  int tot = 0;
  for (int c = 0; c < 8; c++) {
    int v = histG[(c * 64 + lane) * 16 + w];
#pragma unroll
    for (int d = 1; d < 64; d <<= 1) v += __shfl_xor(v, d);
    tot += v;
  }
  if (lane == 0) scnt[w] = tot;
  __syncthreads();
  // expert pair-base and tile-slot base (each lane recomputes; trivial)
  int eb = 0, tb = 0;
  for (int j = 0; j < w; j++) { eb += scnt[j]; tb += (scnt[j] + TM - 1) / TM; }
  int myCnt = scnt[w];
  if (lane == 0) cnt[w] = myCnt;
  // pass 2: per-router-block global pair bases
  int carry = eb;
  for (int c = 0; c < 8; c++) {
    int idx = (c * 64 + lane) * 16 + w;
    int v = histG[idx];
    int incl = v;
#pragma unroll
    for (int d = 1; d < 64; d <<= 1) { int u = __shfl_up(incl, d); if (lane >= d) incl += u; }
    baseG[idx] = carry + incl - v;
    carry += __shfl(incl, 63);
  }
  // dense tile list (sorted by expert)
  int ntile = (myCnt + TM - 1) / TM;
  for (int l = lane; l < ntile; l += 64) {
    tileE[tb + l] = w;
    tileS[tb + l] = eb + l * TM;
    tileN[tb + l] = min(TM, myCnt - l * TM);
  }
}

// ------------- router phase 3: scatter token ids / weights -----------------
__global__ void k_scatter(const int* __restrict__ topi, const float2* __restrict__ topw,
                          const int* __restrict__ baseG,
                          unsigned short* __restrict__ tokG, float* __restrict__ wgtG) {
  __shared__ int loc[16];
  int tid = threadIdx.x;
  if (tid < 16) loc[tid] = 0;
  __syncthreads();
  int t = blockIdx.x * 64 + tid;
  int pk = topi[t];
  float2 w = topw[t];
  int i0 = pk & 255, i1 = (pk >> 8) & 255;
  int s0 = baseG[blockIdx.x * 16 + i0] + atomicAdd(&loc[i0], 1);
  tokG[s0] = (unsigned short)t; wgtG[s0] = w.x;
  int s1 = baseG[blockIdx.x * 16 + i1] + atomicAdd(&loc[i1], 1);
  tokG[s1] = (unsigned short)t; wgtG[s1] = w.y;
}

// ------------- pack x rows into expert-sorted xg (bf16), zero-pad tail -----
__global__ __launch_bounds__(256) void k_gather(
    const float* __restrict__ x, const unsigned short* __restrict__ tokG,
    unsigned short* __restrict__ xg) {
  int wave = threadIdx.x >> 6, lane = threadIdx.x & 63;
  int p = blockIdx.x * 4 + wave;
  unsigned short* op = xg + (size_t)p * DIN + lane * 8;
  if (p < 2 * NTOK) {
    int t = tokG[p];
    const float* xr = x + (size_t)t * DIN + lane * 8;
    float4 a = *(const float4*)xr, b = *(const float4*)(xr + 4);
    union { short8 v; unsigned short u[8]; } o;
    o.u[0] = f2bf(a.x); o.u[1] = f2bf(a.y); o.u[2] = f2bf(a.z); o.u[3] = f2bf(a.w);
    o.u[4] = f2bf(b.x); o.u[5] = f2bf(b.y); o.u[6] = f2bf(b.z); o.u[7] = f2bf(b.w);
    *(short8*)op = o.v;
  } else {
    *(short8*)op = (short8){0, 0, 0, 0, 0, 0, 0, 0};
  }
}

// --------- fused grouped expert kernel: out += w * (relu(x W1 + b1) W2 + b2)
// Tile M=128 pairs x N=256 out, hidden chunk HC=128 (8 chunks), BK=64.
// Dense tile list, XCD-grouped (b&7 = XCD, tiles sorted by expert).
// 4 waves 2x2. LDS: wbuf 32K phase-aliased + hs 32K -> 2 blocks/CU.
__global__ __launch_bounds__(256, 2) void k_moe(
    const unsigned short* __restrict__ xg, const unsigned short* __restrict__ w1t,
    const unsigned short* __restrict__ w2t, const float* __restrict__ b1,
    const float* __restrict__ b2, const int* __restrict__ tileE,
    const int* __restrict__ tileS, const int* __restrict__ tileN,
    const unsigned short* __restrict__ tokG, const float* __restrict__ wgtG,
    float* __restrict__ out) {
  int bid = blockIdx.x;
  int tidx = (bid >> 3) + (bid & 7) * (MAXTILE / 8);  // XCD-grouped tile pick
  int e = tileE[tidx];
  if (e < 0) return;
  int start = tileS[tidx], nv = tileN[tidx];
  __shared__ unsigned short wbuf[16384];   // 32 KB phase-aliased
  __shared__ unsigned short hs[16384];     // 32 KB h chunk [128 x 128]
  __shared__ int stok[TM];
  __shared__ float swgt[TM];
  int tid = threadIdx.x;
  if (tid < TM) {
    bool v = tid < nv;
    stok[tid] = v ? (int)tokG[start + tid] : 0;
    swgt[tid] = v ? wgtG[start + tid] : 0.f;
  }
  __syncthreads();
  int wave = tid >> 6, lane = tid & 63, quad = lane >> 4, l16 = lane & 15;
  int wm = wave & 1, wn = wave >> 1;
  // staging: thread owns 16B chunk at (row = j*32 + srow, lds slot = tid&7)
  int srow = tid >> 3;
  int c8 = (tid & 7) ^ (srow & 7);         // inverse swizzle on source column
  const unsigned short* gx = xg + ((size_t)start + srow) * DIN + c8 * 8;  // +j*32*DIN
  const unsigned short* w1e = w1t + (size_t)e * HID * DIN;   // [h][d]
  const unsigned short* w2e = w2t + (size_t)e * DOUT * HID;  // [o][h]
  const unsigned short* gb1 = w1e + (size_t)srow * DIN + c8 * 8;
  const unsigned short* gb2 = w2e + (size_t)srow * HID + c8 * 8;
  f32x4 acc2[4][8];
#pragma unroll
  for (int nt = 0; nt < 8; nt++) {
    float bv = b2[e * DOUT + wn * 128 + nt * 16 + l16];
#pragma unroll
    for (int mt = 0; mt < 4; mt++) acc2[mt][nt] = (f32x4){bv, bv, bv, bv};
  }
  for (int hc = 0; hc < 8; hc++) {
    // ========== GEMM1: h[128x128] = x[128x512] @ W1T-chunk, +b1, relu ======
    f32x4 acc1[4][4];
#pragma unroll
    for (int nt = 0; nt < 4; nt++) {
      float bv = b1[e * HID + hc * 128 + wn * 64 + nt * 16 + l16];
#pragma unroll
      for (int mt = 0; mt < 4; mt++) acc1[mt][nt] = (f32x4){bv, bv, bv, bv};
    }
    for (int ks = 0; ks < 8; ks++) {
      __syncthreads();                     // wbuf readers (prev slab / b2s) done
#pragma unroll
      for (int j = 0; j < 4; j++)
        gld16(wbuf + ((size_t)j * 256 + tid) * 8,
              gx + (size_t)j * 32 * DIN + ks * 64);
#pragma unroll
      for (int j = 0; j < 4; j++)
        gld16(wbuf + 8192 + ((size_t)j * 256 + tid) * 8,
              gb1 + ((size_t)hc * 128 + j * 32) * DIN + ks * 64);
      __syncthreads();                     // DMA drained
#pragma unroll
      for (int ki2 = 0; ki2 < 2; ki2++) {
        int cq = ki2 * 4 + quad;
        short8 af[4], bf[4];
#pragma unroll
        for (int mt = 0; mt < 4; mt++) {
          int r = wm * 64 + mt * 16 + l16;
          af[mt] = *(const short8*)(wbuf + (r * 8 + (cq ^ (r & 7))) * 8);
        }
#pragma unroll
        for (int nt = 0; nt < 4; nt++) {
          int r = wn * 64 + nt * 16 + l16;
          bf[nt] = *(const short8*)(wbuf + 8192 + (r * 8 + (cq ^ (r & 7))) * 8);
        }
#pragma unroll
        for (int mt = 0; mt < 4; mt++)
#pragma unroll
          for (int nt = 0; nt < 4; nt++)
            acc1[mt][nt] = __builtin_amdgcn_mfma_f32_16x16x32_bf16(
                af[mt], bf[nt], acc1[mt][nt], 0, 0, 0);
      }
    }
    // relu + bf16 -> swizzled hs
#pragma unroll
    for (int mt = 0; mt < 4; mt++) {
#pragma unroll
      for (int nt = 0; nt < 4; nt++) {
        int col = wn * 64 + nt * 16 + l16;
        int c16 = col >> 3, co = col & 7;
#pragma unroll
        for (int r4 = 0; r4 < 4; r4++) {
          int r = wm * 64 + mt * 16 + quad * 4 + r4;
          float v = acc1[mt][nt][r4];
          hs[(r * 16 + (c16 ^ (r & 15))) * 8 + co] = f2bf(v > 0.f ? v : 0.f);
        }
      }
    }
    // ========== GEMM2: acc2 += h[128x128] @ W2T-chunk =======================
    for (int k2 = 0; k2 < 2; k2++) {
      __syncthreads();                     // hs written; prev wbuf reads done
#pragma unroll
      for (int j = 0; j < 8; j++)
        gld16(wbuf + ((size_t)j * 256 + tid) * 8,
              gb2 + (size_t)j * 32 * HID + hc * 128 + k2 * 64);
      __syncthreads();
#pragma unroll
      for (int ki2 = 0; ki2 < 2; ki2++) {
        int cq = ki2 * 4 + quad;
        int ch = k2 * 8 + cq;
        short8 af[4];
#pragma unroll
        for (int mt = 0; mt < 4; mt++) {
          int r = wm * 64 + mt * 16 + l16;
          af[mt] = *(const short8*)(hs + (r * 16 + (ch ^ (r & 15))) * 8);
        }
#pragma unroll
        for (int g = 0; g < 2; g++) {      // nt-grouped: caps live B-frags at 4
          short8 bf[4];
#pragma unroll
          for (int nt = 0; nt < 4; nt++) {
            int r = wn * 128 + g * 64 + nt * 16 + l16;
            bf[nt] = *(const short8*)(wbuf + (r * 8 + (cq ^ (r & 7))) * 8);
          }
#pragma unroll
          for (int mt = 0; mt < 4; mt++)
#pragma unroll
            for (int nt = 0; nt < 4; nt++)
              acc2[mt][g * 4 + nt] = __builtin_amdgcn_mfma_f32_16x16x32_bf16(
                  af[mt], bf[nt], acc2[mt][g * 4 + nt], 0, 0, 0);
        }
      }
    }
  }
  // ---- epilogue: gate-weighted atomic accumulate ----
#pragma unroll
  for (int mt = 0; mt < 4; mt++) {
#pragma unroll
    for (int r4 = 0; r4 < 4; r4++) {
      int m = wm * 64 + mt * 16 + quad * 4 + r4;
      float wv = swgt[m];
      if (wv != 0.f) {
        int t = stok[m];
        float* op = out + (size_t)t * DOUT + wn * 128 + l16;
#pragma unroll
        for (int nt = 0; nt < 8; nt++)
          atomicAdd(op + nt * 16, acc2[mt][nt][r4] * wv);
      }
    }
  }
}

extern "C" void kernel_launch(void* const* d_in, const int* in_sizes, int n_in,
                              void* d_out, int out_size, void* d_ws, size_t ws_size,
                              hipStream_t stream) {
  (void)in_sizes; (void)n_in; (void)ws_size;
  const float* x     = (const float*)d_in[0];
  const float* spike = (const float*)d_in[1];
  const float* Wr    = (const float*)d_in[2];
  const float* br    = (const float*)d_in[3];
  const float* W1    = (const float*)d_in[4];
  const float* b1    = (const float*)d_in[5];
  const float* W2    = (const float*)d_in[6];
  const float* b2    = (const float*)d_in[7];
  float* out = (float*)d_out;
  char* ws = (char*)d_ws;
  // workspace layout (bytes)
  unsigned short* xg   = (unsigned short*)(ws + 0);          // 69,206,016 (67584 rows)
  unsigned short* w1t  = (unsigned short*)(ws + 69206016);   // 10,485,760
  unsigned short* w2t  = (unsigned short*)(ws + 79691776);   //  5,242,880
  float* wrt           = (float*)(ws + 84934656);            //     20,480
  int*   cnt           = (int*)(ws + 84955136);              //         64
  unsigned short* tokG = (unsigned short*)(ws + 84955200);   //    135,168 (padded)
  float* wgtG          = (float*)(ws + 85090368);            //    270,336 (padded)
  int*   topi          = (int*)(ws + 85360704);              //    131,072
  float2* topw         = (float2*)(ws + 85491776);           //    262,144
  int*   histG         = (int*)(ws + 85753920);              //     32,768
  int*   baseG         = (int*)(ws + 85786688);              //     32,768
  int*   tileE         = (int*)(ws + 85819456);              //      2,112
  int*   tileS         = (int*)(ws + 85821568);              //      2,112
  int*   tileN         = (int*)(ws + 85823680);              //      2,112

  hipMemsetAsync(out, 0, (size_t)out_size * sizeof(float), stream);
  k_transpose_wr<<<1, 256, 0, stream>>>(Wr, wrt);
  k_transpose_conv<<<dim3(16, 8, 10), 256, 0, stream>>>(W1, w1t, DIN, HID);
  k_transpose_conv<<<dim3(4, 16, 10), 256, 0, stream>>>(W2, w2t, HID, DOUT);
  k_router<<<512, 256, 0, stream>>>(x, spike, wrt, br, topi, topw, histG);
  k_scan<<<1, 640, 0, stream>>>(histG, baseG, cnt, tileE, tileS, tileN);
  k_scatter<<<512, 64, 0, stream>>>(topi, topw, baseG, tokG, wgtG);
  k_gather<<<16896, 256, 0, stream>>>(x, tokG, xg);
  k_moe<<<MAXTILE, 256, 0, stream>>>(xg, w1t, w2t, b1, b2, tileE, tileS, tileN,
                                     tokG, wgtG, out);
}

// Round 5
// 431.792 us; speedup vs baseline: 1.6873x; 1.6084x over previous
//
#include <hip/hip_runtime.h>
#include <hip/hip_bf16.h>
#include <stdint.h>
#include <stddef.h>

typedef __attribute__((ext_vector_type(8))) short short8;
typedef __attribute__((ext_vector_type(4))) float f32x4;

#define NTOK 32768
#define DIN 512
#define HID 1024
#define DOUT 256
#define NEXP 10
#define TM 128
#define MAXTILE 528   // 8 XCD groups x 66
#define KRES 320      // x K-cols resident in LDS; rest (192) in registers

__device__ __forceinline__ unsigned short f2bf(float f) {
  unsigned int u = __float_as_uint(f);
  u += 0x7fffu + ((u >> 16) & 1u);   // round-to-nearest-even
  return (unsigned short)(u >> 16);
}

// async 16B/lane global->LDS DMA (dest = wave-uniform base + lane*16)
__device__ __forceinline__ void gld16(void* lds, const void* g) {
  __builtin_amdgcn_global_load_lds(
      (const __attribute__((address_space(1))) unsigned int*)g,
      (__attribute__((address_space(3))) unsigned int*)lds, 16, 0, 0);
}

// ---------- fused prep: WrT + W1->[e][h][d] bf16 + W2->[e][o][h] bf16 ------
__global__ __launch_bounds__(256) void k_prep(
    const float* __restrict__ wr, const float* __restrict__ w1,
    const float* __restrict__ w2, float* __restrict__ wrt,
    unsigned short* __restrict__ w1t, unsigned short* __restrict__ w2t) {
  __shared__ unsigned short tile[64][72];
  int b = blockIdx.x, tid = threadIdx.x;
  if (b >= 1920) {   // Wr transpose [512][10] -> [10][512]
    for (int i = tid; i < DIN * NEXP; i += 256) {
      int d = i / NEXP, e = i % NEXP;
      wrt[e * DIN + d] = wr[i];
    }
    return;
  }
  const float* in; unsigned short* out; int R, C, bx, by, bz;
  if (b < 1280) { in = w1; out = w1t; R = DIN; C = HID; bx = b & 15; by = (b >> 4) & 7; bz = b >> 7; }
  else { int b2 = b - 1280; in = w2; out = w2t; R = HID; C = DOUT; bx = b2 & 3; by = (b2 >> 2) & 15; bz = b2 >> 6; }
  const float* ip = in + ((size_t)bz * R + by * 64) * C + bx * 64;
  int r = tid >> 2, c0 = (tid & 3) * 16;
  const float* p = ip + (size_t)r * C + c0;
#pragma unroll
  for (int j = 0; j < 16; j += 4) {
    float4 v = *(const float4*)(p + j);
    tile[r][c0 + j + 0] = f2bf(v.x);
    tile[r][c0 + j + 1] = f2bf(v.y);
    tile[r][c0 + j + 2] = f2bf(v.z);
    tile[r][c0 + j + 3] = f2bf(v.w);
  }
  __syncthreads();
  unsigned short* op = out + ((size_t)bz * C + bx * 64) * R + by * 64;
  int c = tid >> 2, r0 = (tid & 3) * 16;
  unsigned short* q = op + (size_t)c * R + r0;
  union { short8 v; unsigned short u[8]; } t0, t1;
#pragma unroll
  for (int j = 0; j < 8; j++) { t0.u[j] = tile[r0 + j][c]; t1.u[j] = tile[r0 + 8 + j][c]; }
  *(short8*)(q) = t0.v;
  *(short8*)(q + 8) = t1.v;
}

// ------------- router: top-2 + per-block hist + x->bf16 (xb) ---------------
__global__ __launch_bounds__(256) void k_router(
    const float* __restrict__ x, const float* __restrict__ spike,
    const float* __restrict__ wrt, const float* __restrict__ br,
    unsigned short* __restrict__ xb, int* __restrict__ topi,
    float2* __restrict__ topw, int* __restrict__ histG) {
  __shared__ int hist[16];
  int tid = threadIdx.x, wave = tid >> 6, lane = tid & 63;
  if (tid < 16) hist[tid] = 0;
  __syncthreads();
  for (int t = 0; t < 16; t++) {
    int b = blockIdx.x * 64 + wave * 16 + t;
    const float* xr = x + (size_t)b * DIN;
    float xv[8];
#pragma unroll
    for (int k = 0; k < 8; k++) xv[k] = xr[lane + 64 * k];   // coalesced
    unsigned short* xo = xb + (size_t)b * DIN;
#pragma unroll
    for (int k = 0; k < 8; k++) xo[lane + 64 * k] = f2bf(xv[k]);
    float lg[NEXP];
#pragma unroll
    for (int e = 0; e < NEXP; e++) {
      const float* w = wrt + e * DIN;
      float s = 0.f;
#pragma unroll
      for (int k = 0; k < 8; k++) s += xv[k] * w[lane + 64 * k];
      lg[e] = s;
    }
#pragma unroll
    for (int off = 32; off > 0; off >>= 1) {
#pragma unroll
      for (int e = 0; e < NEXP; e++) lg[e] += __shfl_xor(lg[e], off);
    }
    float sv = spike[(size_t)b * 16 + (lane & 15)];
    sv += __shfl_xor(sv, 8); sv += __shfl_xor(sv, 4);
    sv += __shfl_xor(sv, 2); sv += __shfl_xor(sv, 1);
    float avg = sv * 0.0625f;
#pragma unroll
    for (int e = 0; e < NEXP; e++) lg[e] += br[e];
    lg[8] += avg; lg[9] += avg;
    float mx = lg[0];
#pragma unroll
    for (int e = 1; e < NEXP; e++) mx = fmaxf(mx, lg[e]);
    float p[NEXP], ps = 0.f;
#pragma unroll
    for (int e = 0; e < NEXP; e++) { p[e] = __expf(lg[e] - mx); ps += p[e]; }
    int i0 = 0; float p0 = p[0];
#pragma unroll
    for (int e = 1; e < NEXP; e++) if (p[e] > p0) { p0 = p[e]; i0 = e; }
    float p1 = -1.f; int i1 = 0;
#pragma unroll
    for (int e = 0; e < NEXP; e++) if (e != i0 && p[e] > p1) { p1 = p[e]; i1 = e; }
    float inv = 1.f / (p0 + p1 + ps * 1e-9f);
    if (lane == 0) {
      topi[b] = i0 | (i1 << 8);
      topw[b] = make_float2(p0 * inv, p1 * inv);
      atomicAdd(&hist[i0], 1); atomicAdd(&hist[i1], 1);
    }
  }
  __syncthreads();
  if (tid < 16) histG[blockIdx.x * 16 + tid] = hist[tid];
}

// -------- scan: global pair bases + dense XCD-groupable tile list ----------
__global__ void k_scan(const int* __restrict__ histG, int* __restrict__ baseG,
                       int* __restrict__ tileE, int* __restrict__ tileS,
                       int* __restrict__ tileN) {
  __shared__ int scnt[16];
  int tid = threadIdx.x;
  int w = tid >> 6, lane = tid & 63;
  for (int i = tid; i < MAXTILE; i += 640) tileE[i] = -1;
  int tot = 0;
  for (int c = 0; c < 8; c++) {
    int v = histG[(c * 64 + lane) * 16 + w];
#pragma unroll
    for (int d = 1; d < 64; d <<= 1) v += __shfl_xor(v, d);
    tot += v;
  }
  if (lane == 0) scnt[w] = tot;
  __syncthreads();
  int eb = 0, tb = 0;
  for (int j = 0; j < w; j++) { eb += scnt[j]; tb += (scnt[j] + TM - 1) / TM; }
  int myCnt = scnt[w];
  int carry = eb;
  for (int c = 0; c < 8; c++) {
    int idx = (c * 64 + lane) * 16 + w;
    int v = histG[idx];
    int incl = v;
#pragma unroll
    for (int d = 1; d < 64; d <<= 1) { int u = __shfl_up(incl, d); if (lane >= d) incl += u; }
    baseG[idx] = carry + incl - v;
    carry += __shfl(incl, 63);
  }
  int ntile = (myCnt + TM - 1) / TM;
  for (int l = lane; l < ntile; l += 64) {
    tileE[tb + l] = w;
    tileS[tb + l] = eb + l * TM;
    tileN[tb + l] = min(TM, myCnt - l * TM);
  }
}

// ------------- scatter token ids / weights into expert-sorted lists --------
__global__ void k_scatter(const int* __restrict__ topi, const float2* __restrict__ topw,
                          const int* __restrict__ baseG,
                          unsigned short* __restrict__ tokG, float* __restrict__ wgtG) {
  __shared__ int loc[16];
  int tid = threadIdx.x;
  if (tid < 16) loc[tid] = 0;
  __syncthreads();
  int t = blockIdx.x * 64 + tid;
  int pk = topi[t];
  float2 w = topw[t];
  int i0 = pk & 255, i1 = (pk >> 8) & 255;
  int s0 = baseG[blockIdx.x * 16 + i0] + atomicAdd(&loc[i0], 1);
  tokG[s0] = (unsigned short)t; wgtG[s0] = w.x;
  int s1 = baseG[blockIdx.x * 16 + i1] + atomicAdd(&loc[i1], 1);
  tokG[s1] = (unsigned short)t; wgtG[s1] = w.y;
}

// --------- fused expert kernel, x-resident structure -----------------------
// 512 thr / 8 waves, 1 block/CU. x tile: K<320 in LDS (staged ONCE), K>=320
// in per-wave A-frag registers. Weights via dbuf wbuf, 1 barrier per slab
// (DMA for slab s+1 issued at top of slab s => overlaps compute).
// GEMM1 waves 4x2 (wave 32m x 64h), GEMM2 waves 2x4 (wave 64m x 64o).
__global__ __launch_bounds__(512, 2) void k_moe(
    const unsigned short* __restrict__ xb, const unsigned short* __restrict__ w1t,
    const unsigned short* __restrict__ w2t, const float* __restrict__ b1,
    const float* __restrict__ b2, const int* __restrict__ tileE,
    const int* __restrict__ tileS, const int* __restrict__ tileN,
    const unsigned short* __restrict__ tokG, const float* __restrict__ wgtG,
    float* __restrict__ out) {
  int bid = blockIdx.x;
  int tidx = (bid >> 3) + (bid & 7) * (MAXTILE / 8);  // XCD-grouped tiles
  int e = tileE[tidx];
  if (e < 0) return;
  int start = tileS[tidx], nv = tileN[tidx];
  __shared__ __attribute__((aligned(16))) unsigned short xs[128 * 320];   // 80 KB
  __shared__ __attribute__((aligned(16))) unsigned short hs[128 * 128];   // 32 KB
  __shared__ __attribute__((aligned(16))) unsigned short wbuf[2 * 10240]; // 40 KB
  int tid = threadIdx.x;
  int wave = tid >> 6, lane = tid & 63, quad = lane >> 4, l16 = lane & 15;
  int wm1 = wave & 3, wh = wave >> 2;   // GEMM1: 4 x 2
  int wm2 = wave & 1, wo = wave >> 1;   // GEMM2: 2 x 4
  const unsigned short* w1e = w1t + (size_t)e * HID * DIN;   // [h][d]
  const unsigned short* w2e = w2t + (size_t)e * DOUT * HID;  // [o][h]

  // W-slab DMA: i in [0,8) = W1 [128h x 64k] (1024 ch); i in [8,12) =
  // W2 [256o x 32k] rows padded to 5 chunks (1280 ch). Dest half = i&1.
  auto issue = [&](int hc, int i) {
    unsigned short* dst = wbuf + (i & 1) * 10240;
    if (i < 8) {
#pragma unroll
      for (int j = 0; j < 2; j++) {
        int L = j * 512 + tid;
        int row = L >> 3, c = L & 7;
        gld16(dst + (size_t)L * 8,
              w1e + (size_t)(hc * 128 + row) * DIN + i * 64 + (c ^ (row & 7)) * 8);
      }
    } else {
      int k2 = i - 8;
#pragma unroll
      for (int j = 0; j < 3; j++) {
        int L = j * 512 + tid;
        if (L < 1280) {
          int row = L / 5, c = L % 5;
          int cc = c < 4 ? c : 0;   // pad chunk: harmless dup, never read
          gld16(dst + (size_t)L * 8,
                w2e + (size_t)row * HID + hc * 128 + k2 * 32 + cc * 8);
        }
      }
    }
  };

  // ---- stage xs (once): 5120 chunks, 10 per thread
  for (int j = 0; j < 10; j++) {
    int L = j * 512 + tid;
    int row = L / 40, c = L % 40;
    int src = (c & ~7) | ((c & 7) ^ (row & 7));
    int tok = tokG[start + (row < nv ? row : 0)];
    gld16(xs + (size_t)L * 8, xb + (size_t)tok * DIN + src * 8);
  }
  // ---- x tail K in [320,512): per-wave A-frag registers
  short8 xt[2][6];
#pragma unroll
  for (int mf = 0; mf < 2; mf++) {
    int m = wm1 * 32 + mf * 16 + l16;
    int tok = tokG[start + (m < nv ? m : 0)];
    const unsigned short* xp = xb + (size_t)tok * DIN + KRES + quad * 8;
#pragma unroll
    for (int kc = 0; kc < 6; kc++) xt[mf][kc] = *(const short8*)(xp + kc * 32);
  }
  issue(0, 0);

  f32x4 acc2[4][4];   // [mf2][of]
#pragma unroll
  for (int of = 0; of < 4; of++) {
    float bv = b2[e * DOUT + wo * 64 + of * 16 + l16];
#pragma unroll
    for (int mf2 = 0; mf2 < 4; mf2++) acc2[mf2][of] = (f32x4){bv, bv, bv, bv};
  }

  for (int hc = 0; hc < 8; hc++) {
    f32x4 acc1[2][4];   // [mf][hf]
#pragma unroll
    for (int hf = 0; hf < 4; hf++) {
      float bv = b1[e * HID + hc * 128 + wh * 64 + hf * 16 + l16];
#pragma unroll
      for (int mf = 0; mf < 2; mf++) acc1[mf][hf] = (f32x4){bv, bv, bv, bv};
    }
    // ===== GEMM1: 8 slabs of [128h x 64k] ====================
#pragma unroll
    for (int i = 0; i < 8; i++) {
      __syncthreads();                      // drains DMA(slab i), frees other half
      issue(hc, i + 1);                     // i==7 -> first G2 slab
      const unsigned short* wb = wbuf + (i & 1) * 10240;
#pragma unroll
      for (int kk = 0; kk < 2; kk++) {
        short8 bf[4];
#pragma unroll
        for (int hf = 0; hf < 4; hf++) {
          int r = wh * 64 + hf * 16 + l16;
          bf[hf] = *(const short8*)(wb + ((size_t)r * 8 + ((kk * 4 + quad) ^ (r & 7))) * 8);
        }
        if (i < 5) {
          int c0 = i * 8 + kk * 4 + quad;
          short8 af[2];
#pragma unroll
          for (int mf = 0; mf < 2; mf++) {
            int r = wm1 * 32 + mf * 16 + l16;
            int cs = (c0 & ~7) | ((c0 & 7) ^ (r & 7));
            af[mf] = *(const short8*)(xs + ((size_t)r * 40 + cs) * 8);
          }
#pragma unroll
          for (int mf = 0; mf < 2; mf++)
#pragma unroll
            for (int hf = 0; hf < 4; hf++)
              acc1[mf][hf] = __builtin_amdgcn_mfma_f32_16x16x32_bf16(
                  af[mf], bf[hf], acc1[mf][hf], 0, 0, 0);
        } else {
          int kc = (i - 5) * 2 + kk;
#pragma unroll
          for (int mf = 0; mf < 2; mf++)
#pragma unroll
            for (int hf = 0; hf < 4; hf++)
              acc1[mf][hf] = __builtin_amdgcn_mfma_f32_16x16x32_bf16(
                  xt[mf][kc], bf[hf], acc1[mf][hf], 0, 0, 0);
        }
      }
    }
    // relu + bf16 -> swizzled hs [128 x 128]
#pragma unroll
    for (int mf = 0; mf < 2; mf++)
#pragma unroll
      for (int hf = 0; hf < 4; hf++)
#pragma unroll
        for (int r4 = 0; r4 < 4; r4++) {
          int r = wm1 * 32 + mf * 16 + quad * 4 + r4;
          int col = wh * 64 + hf * 16 + l16;
          int c16 = col >> 3, co = col & 7;
          float v = acc1[mf][hf][r4];
          hs[(size_t)r * 128 + ((c16 ^ (r & 7)) << 3) + co] = f2bf(v > 0.f ? v : 0.f);
        }
    // ===== GEMM2: 4 slabs of [256o x 32k] ====================
#pragma unroll
    for (int k2 = 0; k2 < 4; k2++) {
      __syncthreads();                      // covers hs writes + DMA drain
      if (k2 < 3) issue(hc, 9 + k2);
      else if (hc < 7) issue(hc + 1, 0);
      const unsigned short* wb = wbuf + ((8 + k2) & 1) * 10240;
      short8 ah[4];
#pragma unroll
      for (int mf2 = 0; mf2 < 4; mf2++) {
        int r = wm2 * 64 + mf2 * 16 + l16;
        ah[mf2] = *(const short8*)(hs + ((size_t)r * 16 + ((k2 * 4 + quad) ^ (r & 7))) * 8);
      }
      short8 bo[4];
#pragma unroll
      for (int of = 0; of < 4; of++) {
        int row = wo * 64 + of * 16 + l16;
        bo[of] = *(const short8*)(wb + ((size_t)row * 5 + quad) * 8);
      }
#pragma unroll
      for (int mf2 = 0; mf2 < 4; mf2++)
#pragma unroll
        for (int of = 0; of < 4; of++)
          acc2[mf2][of] = __builtin_amdgcn_mfma_f32_16x16x32_bf16(
              ah[mf2], bo[of], acc2[mf2][of], 0, 0, 0);
    }
  }
  // ---- epilogue: gate-weighted atomic accumulate ----
#pragma unroll
  for (int mf2 = 0; mf2 < 4; mf2++)
#pragma unroll
    for (int r4 = 0; r4 < 4; r4++) {
      int m = wm2 * 64 + mf2 * 16 + quad * 4 + r4;
      if (m < nv) {
        int tok = tokG[start + m];
        float wv = wgtG[start + m];
        float* op = out + (size_t)tok * DOUT + wo * 64 + l16;
#pragma unroll
        for (int of = 0; of < 4; of++)
          atomicAdd(op + of * 16, acc2[mf2][of][r4] * wv);
      }
    }
}

extern "C" void kernel_launch(void* const* d_in, const int* in_sizes, int n_in,
                              void* d_out, int out_size, void* d_ws, size_t ws_size,
                              hipStream_t stream) {
  (void)in_sizes; (void)n_in; (void)ws_size;
  const float* x     = (const float*)d_in[0];
  const float* spike = (const float*)d_in[1];
  const float* Wr    = (const float*)d_in[2];
  const float* br    = (const float*)d_in[3];
  const float* W1    = (const float*)d_in[4];
  const float* b1    = (const float*)d_in[5];
  const float* W2    = (const float*)d_in[6];
  const float* b2    = (const float*)d_in[7];
  float* out = (float*)d_out;
  char* ws = (char*)d_ws;
  unsigned short* xb   = (unsigned short*)(ws + 0);          // 33,554,432
  unsigned short* w1t  = (unsigned short*)(ws + 33554432);   // 10,485,760
  unsigned short* w2t  = (unsigned short*)(ws + 44040192);   //  5,242,880
  float* wrt           = (float*)(ws + 49283072);            //     20,480
  unsigned short* tokG = (unsigned short*)(ws + 49303552);   //    135,168
  float* wgtG          = (float*)(ws + 49438720);            //    270,336
  int*   topi          = (int*)(ws + 49709056);              //    131,072
  float2* topw         = (float2*)(ws + 49840128);           //    262,144
  int*   histG         = (int*)(ws + 50102272);              //     32,768
  int*   baseG         = (int*)(ws + 50135040);              //     32,768
  int*   tileE         = (int*)(ws + 50167808);              //      2,112
  int*   tileS         = (int*)(ws + 50169920);              //      2,112
  int*   tileN         = (int*)(ws + 50172032);              //      2,112

  hipMemsetAsync(out, 0, (size_t)out_size * sizeof(float), stream);
  k_prep<<<1921, 256, 0, stream>>>(Wr, W1, W2, wrt, w1t, w2t);
  k_router<<<512, 256, 0, stream>>>(x, spike, wrt, br, xb, topi, topw, histG);
  k_scan<<<1, 640, 0, stream>>>(histG, baseG, tileE, tileS, tileN);
  k_scatter<<<512, 64, 0, stream>>>(topi, topw, baseG, tokG, wgtG);
  k_moe<<<MAXTILE, 512, 0, stream>>>(xb, w1t, w2t, b1, b2, tileE, tileS, tileN,
                                     tokG, wgtG, out);
}